// Round 6
// baseline (647.176 us; speedup 1.0000x reference)
//
#include <hip/hip_runtime.h>
#include <hip/hip_bf16.h>

#define NGROUPS 131072
#define H 128
#define SG 3            // group size
#define NHEADS 4
#define HD 32
#define GB 16           // groups per block
#define MR 48           // rows per block (= GB*SG)
#define NT 512          // threads per block (8 waves)
#define NLAYERS 2
// weight slots in ws: 0=Ws, then per layer l: 1+3l=Wq_l, 2+3l=Wk_l, 3+3l=Wvo_l
#define NSLOT 7
#define BVO_OFF (NSLOT * H * H)   // u16 offset of f32 bvo[NLAYERS][H] (= bv@Wo)

typedef unsigned short u16;
typedef unsigned int u32;
typedef __bf16 bf16x8 __attribute__((ext_vector_type(8)));
typedef float floatx4 __attribute__((ext_vector_type(4)));

__device__ __forceinline__ float bf2f_lo(u32 u) {
  union { u32 i; float f; } c; c.i = u << 16; return c.f;
}
__device__ __forceinline__ float bf2f_hi(u32 u) {
  union { u32 i; float f; } c; c.i = u & 0xffff0000u; return c.f;
}
// packed f32x2 -> bf16x2 (v_cvt_pk_bf16_f32 on gfx950), RNE
__device__ __forceinline__ u32 f2bf2(float a, float b) {
  __hip_bfloat162 h = __float22bfloat162_rn(make_float2(a, b));
  union { __hip_bfloat162 h; u32 u; } c; c.h = h; return c.u;
}
__device__ __forceinline__ u16 f2bf(float f) {
  union { float f; u32 i; } c; c.f = f;
  u32 x = c.i; x += 0x7fffu + ((x >> 16) & 1u);
  return (u16)(x >> 16);
}

// XOR swizzle on 256B rows. bcol in BYTES; bits 4-6 flipped -> >=8B accesses
// stay in-row.
__device__ __forceinline__ const u16* swz(const u16* base, int row, int bcol) {
  return base + row * H + ((bcol ^ ((row & 7) << 4)) >> 1);
}
__device__ __forceinline__ u16* swz(u16* base, int row, int bcol) {
  return base + row * H + ((bcol ^ ((row & 7) << 4)) >> 1);
}

// ---- transpose+bf16 for the 5 raw weight slots: wt[slot][n][k] = W[k][n] ----
__global__ void wconv_t(const float* __restrict__ Ws, const float* __restrict__ Wq,
                        const float* __restrict__ Wk, u16* __restrict__ wt) {
  int idx = blockIdx.x * 256 + threadIdx.x;   // grid = 5*16384/256 = 320
  int s5 = idx >> 14, rem = idx & 16383;
  int n = rem >> 7, k = rem & 127;
  const float* src; int dst;
  switch (s5) {
    case 0:  src = Ws;         dst = 0; break;
    case 1:  src = Wq;         dst = 1; break;
    case 2:  src = Wk;         dst = 2; break;
    case 3:  src = Wq + H * H; dst = 4; break;
    default: src = Wk + H * H; dst = 5; break;
  }
  wt[dst * (H * H) + rem] = f2bf(src[k * H + n]);
}

// ---- O-projection fusion: Wvo = Wv@Wo (fp32 accum), bvo = bv@Wo ----
// (P·V)·Wo = P·(V·Wo); softmax rows sum to 1 so constants pass through P.
__global__ void wvo_kernel(const float* __restrict__ Wv, const float* __restrict__ Wo,
                           const float* __restrict__ bv, u16* __restrict__ wt) {
  if (blockIdx.x < 128) {
    int idx = blockIdx.x * 256 + threadIdx.x;   // 2*16384
    int l = idx >> 14, rem = idx & 16383;
    int k = rem >> 7, n = rem & 127;
    const float* wv = Wv + l * H * H + k * H;   // row k of Wv[l]
    const float* wo = Wo + l * H * H + n;       // col n of Wo[l]
    float s = 0.f;
#pragma unroll 8
    for (int m = 0; m < H; m++) s += wv[m] * wo[m * H];
    wt[(3 + 3 * l) * (H * H) + n * H + k] = f2bf(s);   // transposed [n][k]
  } else {
    int t = threadIdx.x;                        // 256 = 2 layers x 128 cols
    int l = t >> 7, n = t & 127;
    const float* bvl = bv + l * H;
    const float* wo = Wo + l * H * H + n;
    float s = 0.f;
#pragma unroll 8
    for (int m = 0; m < H; m++) s += bvl[m] * wo[m * H];
    reinterpret_cast<float*>(wt + BVO_OFF)[l * H + n] = s;
  }
}

// NP projections sharing one LDS B-operand. Weight slots consecutive.
// NP<=2 ONLY: NP=4's peak live (48 acc + persistents ~= 140) overflows the
// waves_per_eu(4) 128-reg cap by ~14 regs -> r5's 241 MB scratch traffic.
// NP=2 peak ~= 89 fits with headroom for a-load hoisting.
template <int NP>
__device__ __forceinline__ void multi_proj(const u16* __restrict__ lds,
                                           const u16* __restrict__ w0,
                                           floatx4 acc[NP][3], int m0, int qi, int wrow) {
#pragma unroll
  for (int p = 0; p < NP; p++)
#pragma unroll
    for (int nt = 0; nt < 3; nt++)
      acc[p][nt] = (floatx4){0.f, 0.f, 0.f, 0.f};
#pragma unroll
  for (int kk = 0; kk < 4; kk++) {
    bf16x8 b[3];
#pragma unroll
    for (int nt = 0; nt < 3; nt++)
      b[nt] = *reinterpret_cast<const bf16x8*>(swz(lds, nt * 16 + m0, kk * 64 + qi * 16));
#pragma unroll
    for (int p = 0; p < NP; p++) {
      bf16x8 a = *reinterpret_cast<const bf16x8*>(w0 + (size_t)p * H * H + wrow * H + kk * 32 + qi * 8);
#pragma unroll
      for (int nt = 0; nt < 3; nt++)
        acc[p][nt] = __builtin_amdgcn_mfma_f32_16x16x32_bf16(a, b[nt], acc[p][nt], 0, 0, 0);
    }
  }
}

// store acc+bias as packed bf16, 4 consecutive cols per row -> one b64 write per nt
__device__ __forceinline__ void store_proj(u16* __restrict__ buf, const floatx4 acc[3],
                                           float4 b4, int m0, int colb) {
#pragma unroll
  for (int nt = 0; nt < 3; nt++) {
    uint2 pp;
    pp.x = f2bf2(acc[nt][0] + b4.x, acc[nt][1] + b4.y);
    pp.y = f2bf2(acc[nt][2] + b4.z, acc[nt][3] + b4.w);
    *reinterpret_cast<uint2*>(swz(buf, nt * 16 + m0, colb * 2)) = pp;
  }
}

// pack acc+bias into registers (12 regs) -- lets Q survive across the next
// pass so its store can wait for the barrier without a third mp pass.
__device__ __forceinline__ void pack_proj(u32 pk[3][2], const floatx4 acc[3], float4 b4) {
#pragma unroll
  for (int nt = 0; nt < 3; nt++) {
    pk[nt][0] = f2bf2(acc[nt][0] + b4.x, acc[nt][1] + b4.y);
    pk[nt][1] = f2bf2(acc[nt][2] + b4.z, acc[nt][3] + b4.w);
  }
}
__device__ __forceinline__ void store_packed(u16* __restrict__ buf, const u32 pk[3][2],
                                             int m0, int colb) {
#pragma unroll
  for (int nt = 0; nt < 3; nt++) {
    uint2 pp; pp.x = pk[nt][0]; pp.y = pk[nt][1];
    *reinterpret_cast<uint2*>(swz(buf, nt * 16 + m0, colb * 2)) = pp;
  }
}

__global__ void __launch_bounds__(NT)
__attribute__((amdgpu_waves_per_eu(4)))
dango_kernel(const float* __restrict__ x, const u16* __restrict__ wt,
             const float* __restrict__ bs, const float* __restrict__ bq,
             const float* __restrict__ bk, const float* __restrict__ bo,
             const float* __restrict__ beta, const float* __restrict__ Wp,
             const float* __restrict__ bp, float* __restrict__ out)
{
  // 38.4 KB LDS; waves_per_eu(4) caps at 128 unified regs -> 2 blocks/CU.
  // qbuf multi-role: x/dyn bf16 mirror (B-operand) -> Q.
  __shared__ __align__(16) u16 qbuf[MR][H];
  __shared__ __align__(16) u16 kbuf[MR][H];
  __shared__ __align__(16) u16 vbuf[MR][H];   // holds V' = X@Wvo + bv@Wo
  // attnw (layer phases) UNION rowsc[MR][8] (readout); disjoint lifetimes.
  __shared__ __align__(16) float scratch[GB * NHEADS * SG * 2];   // 384 floats

  const int tid = threadIdx.x;
  const int lane = tid & 63;
  const int wave = tid >> 6;          // 0..7: owns outcols wave*16..wave*16+15
  const int m0 = lane & 15;           // gene-row index within nt-tile
  const int qi = lane >> 4;           // 0..3: 4-col window within wave's 16
  const int colb = wave * 16 + qi * 4;
  const int wrow = wave * 16 + m0;    // weight row (outcol block) this lane loads
  const int row0 = blockIdx.x * MR;
  const float* __restrict__ bvo = reinterpret_cast<const float*>(wt + BVO_OFF);

  float xdyn[3][4];                   // residual fp32: rows nt*16+m0, cols colb..+3
  u32 statpk[3][2];                   // static embedding, packed bf16
  u32 qpk[3][2];                      // Q held packed across the K/V' pass

  // ---- init: x -> xdyn regs + qbuf bf16 mirror ----
#pragma unroll
  for (int nt = 0; nt < 3; nt++) {
    int row = nt * 16 + m0;
    float4 v = *reinterpret_cast<const float4*>(x + (size_t)(row0 + row) * H + colb);
    xdyn[nt][0] = v.x; xdyn[nt][1] = v.y; xdyn[nt][2] = v.z; xdyn[nt][3] = v.w;
    uint2 pp; pp.x = f2bf2(v.x, v.y); pp.y = f2bf2(v.z, v.w);
    *reinterpret_cast<uint2*>(swz(&qbuf[0][0], row, colb * 2)) = pp;
  }
  __syncthreads();

  // ---- phase A: static+Q then K+V', two 2-stream passes (peak 24 acc) ----
  {
    floatx4 acc[2][3];
    multi_proj<2>(&qbuf[0][0], wt, acc, m0, qi, wrow);            // Ws, Wq
    {
      float4 b4 = *reinterpret_cast<const float4*>(bs + colb);
#pragma unroll
      for (int nt = 0; nt < 3; nt++) {
        statpk[nt][0] = f2bf2(fmaxf(acc[0][nt][0] + b4.x, 0.f), fmaxf(acc[0][nt][1] + b4.y, 0.f));
        statpk[nt][1] = f2bf2(fmaxf(acc[0][nt][2] + b4.z, 0.f), fmaxf(acc[0][nt][3] + b4.w, 0.f));
      }
    }
    pack_proj(qpk, acc[1], *reinterpret_cast<const float4*>(bq + colb));
  }
  {
    floatx4 acc[2][3];
    multi_proj<2>(&qbuf[0][0], wt + (size_t)2 * H * H, acc, m0, qi, wrow);  // Wk, Wvo
    store_proj(&kbuf[0][0], acc[0], *reinterpret_cast<const float4*>(bk + colb), m0, colb);
    store_proj(&vbuf[0][0], acc[1], *reinterpret_cast<const float4*>(bvo + colb), m0, colb);
  }
  __syncthreads();   // all waves' B-reads of qbuf(x) complete before Q overwrites
  store_packed(&qbuf[0][0], qpk, m0, colb);
  __syncthreads();

  for (int l = 0; l < NLAYERS; l++) {
    // ---- scores + 2-way softmax, 384 threads (one per (g,h,i,j)) ----
    if (tid < GB * NHEADS * SG * 2) {
      int js = tid & 1;
      int rest = tid >> 1;
      int i = rest % 3;
      int m = rest / 3;          // 0..63
      int h = m & 3, g = m >> 2;
      int j = (i == 0) ? (js ? 2 : 1) : (i == 1) ? (js ? 2 : 0) : (js ? 1 : 0);
      float s = 0.f;
#pragma unroll
      for (int c = 0; c < 4; c++) {
        int bcol = h * 64 + c * 16;
        uint4 qu = *reinterpret_cast<const uint4*>(swz(&qbuf[0][0], g * 3 + i, bcol));
        uint4 ku = *reinterpret_cast<const uint4*>(swz(&kbuf[0][0], g * 3 + j, bcol));
        u32 qs[4] = {qu.x, qu.y, qu.z, qu.w};
        u32 ks[4] = {ku.x, ku.y, ku.z, ku.w};
#pragma unroll
        for (int e = 0; e < 4; e++)
          s += bf2f_lo(qs[e]) * bf2f_lo(ks[e]) + bf2f_hi(qs[e]) * bf2f_hi(ks[e]);
      }
      s *= 0.17677669529663687f;   // 1/sqrt(32)
      float so = __shfl_xor(s, 1); // partner (other j), same wave (384 is wave-aligned)
      float mx = fmaxf(s, so);
      float e = __expf(s - mx), eo = __expf(so - mx);
      scratch[((g * NHEADS + h) * SG + i) * 2 + js] = e / (e + eo);
    }
    __syncthreads();

    // ---- combine: xdyn += beta*(P·V' + bo)  (V' already O-projected) ----
    // Also refreshes the bf16 dyn mirror for the next layer in the same phase.
    {
      float4 bo4 = *reinterpret_cast<const float4*>(bo + l * H + colb);
      const float betal = beta[l];
      const int h = colb >> 5;
#pragma unroll
      for (int nt = 0; nt < 3; nt++) {
        int r = nt * 16 + m0;
        int g = r / 3, i = r - g * 3;
        int j0 = (i == 0) ? 1 : 0;
        int j1 = (i == 2) ? 1 : 2;
        int ai = ((g * NHEADS + h) * SG + i) * 2;
        float a0 = scratch[ai + 0], a1 = scratch[ai + 1];
        uint2 v0 = *reinterpret_cast<const uint2*>(swz(&vbuf[0][0], g * 3 + j0, colb * 2));
        uint2 v1 = *reinterpret_cast<const uint2*>(swz(&vbuf[0][0], g * 3 + j1, colb * 2));
        xdyn[nt][0] += betal * (a0 * bf2f_lo(v0.x) + a1 * bf2f_lo(v1.x) + bo4.x);
        xdyn[nt][1] += betal * (a0 * bf2f_hi(v0.x) + a1 * bf2f_hi(v1.x) + bo4.y);
        xdyn[nt][2] += betal * (a0 * bf2f_lo(v0.y) + a1 * bf2f_lo(v1.y) + bo4.z);
        xdyn[nt][3] += betal * (a0 * bf2f_hi(v0.y) + a1 * bf2f_hi(v1.y) + bo4.w);
        if (l + 1 < NLAYERS) {
          uint2 pp;
          pp.x = f2bf2(xdyn[nt][0], xdyn[nt][1]);
          pp.y = f2bf2(xdyn[nt][2], xdyn[nt][3]);
          *reinterpret_cast<uint2*>(swz(&qbuf[0][0], r, colb * 2)) = pp;
        }
      }
    }
    __syncthreads();   // fences: scratch reads, vbuf reads, qbuf mirror writes

    if (l + 1 < NLAYERS) {
      // ---- Q/K then V' of layer l+1: mp<2> + mp<1> (peak 24 acc) ----
      const size_t base = (size_t)(1 + 3 * (l + 1));
      {
        floatx4 acc[2][3];
        multi_proj<2>(&qbuf[0][0], wt + base * H * H, acc, m0, qi, wrow);    // Wq, Wk
        pack_proj(qpk, acc[0], *reinterpret_cast<const float4*>(bq + (l + 1) * H + colb));
        store_proj(&kbuf[0][0], acc[1], *reinterpret_cast<const float4*>(bk + (l + 1) * H + colb), m0, colb);
      }
      {
        floatx4 acc1[1][3];
        multi_proj<1>(&qbuf[0][0], wt + (base + 2) * H * H, acc1, m0, qi, wrow);  // Wvo
        store_proj(&vbuf[0][0], acc1[0], *reinterpret_cast<const float4*>(bvo + (l + 1) * H + colb), m0, colb);
      }
      __syncthreads();   // B-reads of qbuf(dyn) complete before Q overwrites
      store_packed(&qbuf[0][0], qpk, m0, colb);
      __syncthreads();
    }
  }

  // ---- readout: gene score = sum_c (dyn-stat)^2 * Wp[c]; group mean ----
  float4 wp4 = *reinterpret_cast<const float4*>(Wp + colb);
  float rsum[3];
#pragma unroll
  for (int nt = 0; nt < 3; nt++) {
    float d0 = xdyn[nt][0] - bf2f_lo(statpk[nt][0]);
    float d1 = xdyn[nt][1] - bf2f_hi(statpk[nt][0]);
    float d2 = xdyn[nt][2] - bf2f_lo(statpk[nt][1]);
    float d3 = xdyn[nt][3] - bf2f_hi(statpk[nt][1]);
    rsum[nt] = d0 * d0 * wp4.x + d1 * d1 * wp4.y + d2 * d2 * wp4.z + d3 * d3 * wp4.w;
  }
  // reduce over qi (lane bits 4,5): each row's 16 cols within this wave
#pragma unroll
  for (int nt = 0; nt < 3; nt++) {
    rsum[nt] += __shfl_xor(rsum[nt], 16, 64);
    rsum[nt] += __shfl_xor(rsum[nt], 32, 64);
  }
  // scratch re-used as rowsc[MR][8]; last read (combine) fenced by the
  // post-combine barrier of layer NLAYERS-1
  if (qi == 0) {
#pragma unroll
    for (int nt = 0; nt < 3; nt++)
      scratch[(nt * 16 + m0) * 8 + wave] = rsum[nt];
  }
  __syncthreads();
  if (tid < GB) {
    float s = 0.f;
#pragma unroll
    for (int i = 0; i < SG; i++) {
      int row = tid * 3 + i;
#pragma unroll
      for (int w = 0; w < 8; w++) s += scratch[row * 8 + w];
    }
    out[blockIdx.x * GB + tid] = s * (1.f / 3.f) + bp[0];
  }
}

extern "C" void kernel_launch(void* const* d_in, const int* in_sizes, int n_in,
                              void* d_out, int out_size, void* d_ws, size_t ws_size,
                              hipStream_t stream) {
  const float* x    = (const float*)d_in[0];
  // d_in[1] = batch ids: deterministic repeat(arange(G),3) -> not needed
  const float* Ws   = (const float*)d_in[2];
  const float* bs   = (const float*)d_in[3];
  const float* Wq   = (const float*)d_in[4];
  const float* bq   = (const float*)d_in[5];
  const float* Wk   = (const float*)d_in[6];
  const float* bk   = (const float*)d_in[7];
  const float* Wv   = (const float*)d_in[8];
  const float* bv   = (const float*)d_in[9];
  const float* Wo   = (const float*)d_in[10];
  const float* bo   = (const float*)d_in[11];
  const float* beta = (const float*)d_in[12];
  const float* Wp   = (const float*)d_in[13];
  const float* bp   = (const float*)d_in[14];
  float* out = (float*)d_out;
  u16* wt = (u16*)d_ws;   // 7*16384 bf16 + 2*128 f32 = 230,400 B (ws >= 294,912)

  // ws is re-poisoned before every launch -> convert every call
  wconv_t<<<320, 256, 0, stream>>>(Ws, Wq, Wk, wt);
  wvo_kernel<<<129, 256, 0, stream>>>(Wv, Wo, bv, wt);
  dango_kernel<<<NGROUPS / GB, NT, 0, stream>>>(x, wt, bs, bq, bk, bo, beta, Wp, bp, out);
}

// Round 7
// 531.592 us; speedup vs baseline: 1.2174x; 1.2174x over previous
//
#include <hip/hip_runtime.h>
#include <hip/hip_bf16.h>

#define NGROUPS 131072
#define H 128
#define SG 3            // group size
#define NHEADS 4
#define HD 32
#define GB 16           // groups per block
#define MR 48           // rows per block (= GB*SG)
#define NT 512          // threads per block (8 waves)
#define BP 136          // bf16 LDS row stride; r0-proven (spill-free codegen)
#define NLAYERS 2
// weight slots in ws: 0=Ws, then per layer l: 1+3l=Wq_l, 2+3l=Wk_l, 3+3l=Wvo_l
#define NSLOT 7
#define BVO_OFF (NSLOT * H * H)   // u16 offset of f32 bvo[NLAYERS][H] (= bv@Wo)

typedef unsigned short u16;
typedef unsigned int u32;
typedef __bf16 bf16x8 __attribute__((ext_vector_type(8)));
typedef float floatx4 __attribute__((ext_vector_type(4)));

__device__ __forceinline__ float bf2f_lo(u32 u) {
  union { u32 i; float f; } c; c.i = u << 16; return c.f;
}
__device__ __forceinline__ float bf2f_hi(u32 u) {
  union { u32 i; float f; } c; c.i = u & 0xffff0000u; return c.f;
}
// packed f32x2 -> bf16x2 (v_cvt_pk_bf16_f32 on gfx950), RNE
__device__ __forceinline__ u32 f2bf2(float a, float b) {
  __hip_bfloat162 h = __float22bfloat162_rn(make_float2(a, b));
  union { __hip_bfloat162 h; u32 u; } c; c.h = h; return c.u;
}
__device__ __forceinline__ u16 f2bf(float f) {
  union { float f; u32 i; } c; c.f = f;
  u32 x = c.i; x += 0x7fffu + ((x >> 16) & 1u);
  return (u16)(x >> 16);
}

// ---- transpose+bf16 for the 5 raw weight slots: wt[slot][n][k] = W[k][n] ----
__global__ void wconv_t(const float* __restrict__ Ws, const float* __restrict__ Wq,
                        const float* __restrict__ Wk, u16* __restrict__ wt) {
  int idx = blockIdx.x * 256 + threadIdx.x;   // grid = 5*16384/256 = 320
  int s5 = idx >> 14, rem = idx & 16383;
  int n = rem >> 7, k = rem & 127;
  const float* src; int dst;
  switch (s5) {
    case 0:  src = Ws;         dst = 0; break;
    case 1:  src = Wq;         dst = 1; break;
    case 2:  src = Wk;         dst = 2; break;
    case 3:  src = Wq + H * H; dst = 4; break;
    default: src = Wk + H * H; dst = 5; break;
  }
  wt[dst * (H * H) + rem] = f2bf(src[k * H + n]);
}

// ---- O-projection fusion: Wvo = Wv@Wo (fp32 accum), bvo = bv@Wo ----
// (P·V)·Wo = P·(V·Wo); softmax rows sum to 1 so constants pass through P.
// Eliminates the per-layer O-projection MFMA pass + attn-out LDS round-trip.
__global__ void wvo_kernel(const float* __restrict__ Wv, const float* __restrict__ Wo,
                           const float* __restrict__ bv, u16* __restrict__ wt) {
  if (blockIdx.x < 128) {
    int idx = blockIdx.x * 256 + threadIdx.x;   // 2*16384
    int l = idx >> 14, rem = idx & 16383;
    int k = rem >> 7, n = rem & 127;
    const float* wv = Wv + l * H * H + k * H;   // row k of Wv[l]
    const float* wo = Wo + l * H * H + n;       // col n of Wo[l]
    float s = 0.f;
#pragma unroll 8
    for (int m = 0; m < H; m++) s += wv[m] * wo[m * H];
    wt[(3 + 3 * l) * (H * H) + n * H + k] = f2bf(s);   // transposed [n][k]
  } else {
    int t = threadIdx.x;                        // 256 = 2 layers x 128 cols
    int l = t >> 7, n = t & 127;
    const float* bvl = bv + l * H;
    const float* wo = Wo + l * H * H + n;
    float s = 0.f;
#pragma unroll 8
    for (int m = 0; m < H; m++) s += bvl[m] * wo[m * H];
    reinterpret_cast<float*>(wt + BVO_OFF)[l * H + n] = s;
  }
}

// NP projections sharing one LDS B-operand; results stored IMMEDIATELY after
// the pass (r0-proven pattern). Register model (3 failed pins r1-r3 + r5/r6
// spills): waves_per_eu(4) splits 128 unified into 64 arch + 64 AGPR; acc
// lives in AGPR (48 at NP=4 fits), arch side holds b-frags/a-frags/addressing
// and must NOT carry packed results or acc across barriers (r5: 241 MB,
// r6: 443 MB scratch traffic). Persistent arch state = xdyn+statpk only.
template <int NP>
__device__ __forceinline__ void multi_proj(const u16* __restrict__ lds,
                                           const u16* __restrict__ w0,
                                           floatx4 acc[NP][3], int m0, int qi, int wrow) {
#pragma unroll
  for (int p = 0; p < NP; p++)
#pragma unroll
    for (int nt = 0; nt < 3; nt++)
      acc[p][nt] = (floatx4){0.f, 0.f, 0.f, 0.f};
#pragma unroll
  for (int kk = 0; kk < 4; kk++) {
    bf16x8 b[3];
#pragma unroll
    for (int nt = 0; nt < 3; nt++)
      b[nt] = *reinterpret_cast<const bf16x8*>(lds + (nt * 16 + m0) * BP + kk * 32 + qi * 8);
#pragma unroll
    for (int p = 0; p < NP; p++) {
      bf16x8 a = *reinterpret_cast<const bf16x8*>(w0 + (size_t)p * H * H + wrow * H + kk * 32 + qi * 8);
#pragma unroll
      for (int nt = 0; nt < 3; nt++)
        acc[p][nt] = __builtin_amdgcn_mfma_f32_16x16x32_bf16(a, b[nt], acc[p][nt], 0, 0, 0);
    }
  }
}

// store acc+bias as packed bf16, 4 consecutive cols per row -> one b64 write per nt
__device__ __forceinline__ void store_proj(u16* __restrict__ buf, const floatx4 acc[3],
                                           float4 b4, int m0, int colb) {
#pragma unroll
  for (int nt = 0; nt < 3; nt++) {
    uint2 pp;
    pp.x = f2bf2(acc[nt][0] + b4.x, acc[nt][1] + b4.y);
    pp.y = f2bf2(acc[nt][2] + b4.z, acc[nt][3] + b4.w);
    *reinterpret_cast<uint2*>(buf + (nt * 16 + m0) * BP + colb) = pp;
  }
}

__global__ void __launch_bounds__(NT)
__attribute__((amdgpu_waves_per_eu(4)))
dango_kernel(const float* __restrict__ x, const u16* __restrict__ wt,
             const float* __restrict__ bs, const float* __restrict__ bq,
             const float* __restrict__ bk, const float* __restrict__ bo,
             const float* __restrict__ beta, const float* __restrict__ Wp,
             const float* __restrict__ bp, float* __restrict__ out)
{
  // ~53.8 KB LDS -> 2 blocks/CU. xbf SEPARATE (r0 pattern): every mp pass
  // stores its results immediately; no packed values survive across barriers.
  __shared__ __align__(16) u16 xbf[MR][BP];   // residual bf16 mirror (B-operand)
  __shared__ __align__(16) u16 qbuf[MR][BP];  // Q
  __shared__ __align__(16) u16 kbuf[MR][BP];  // K
  __shared__ __align__(16) u16 vbuf[MR][BP];  // V' = X@Wvo + bv@Wo
  // attnw (layer phases) UNION rowsc[MR][8] (readout); disjoint lifetimes.
  __shared__ __align__(16) float scratch[GB * NHEADS * SG * 2];   // 384 floats

  const int tid = threadIdx.x;
  const int lane = tid & 63;
  const int wave = tid >> 6;          // 0..7: owns outcols wave*16..wave*16+15
  const int m0 = lane & 15;           // gene-row index within nt-tile
  const int qi = lane >> 4;           // 0..3: 4-col window within wave's 16
  const int colb = wave * 16 + qi * 4;
  const int wrow = wave * 16 + m0;    // weight row (outcol block) this lane loads
  const int row0 = blockIdx.x * MR;
  const float* __restrict__ bvo = reinterpret_cast<const float*>(wt + BVO_OFF);

  float xdyn[3][4];                   // residual fp32: rows nt*16+m0, cols colb..+3
  u32 statpk[3][2];                   // static embedding, packed bf16

  // ---- init: x -> xdyn regs + xbf mirror ----
#pragma unroll
  for (int nt = 0; nt < 3; nt++) {
    int row = nt * 16 + m0;
    float4 v = *reinterpret_cast<const float4*>(x + (size_t)(row0 + row) * H + colb);
    xdyn[nt][0] = v.x; xdyn[nt][1] = v.y; xdyn[nt][2] = v.z; xdyn[nt][3] = v.w;
    uint2 pp; pp.x = f2bf2(v.x, v.y); pp.y = f2bf2(v.z, v.w);
    *reinterpret_cast<uint2*>(&xbf[row][colb]) = pp;
  }
  __syncthreads();

  // ---- phase A: static + Q/K/V' of layer 0, ONE 4-stream pass, store-now ----
  {
    floatx4 acc[4][3];
    multi_proj<4>(&xbf[0][0], wt, acc, m0, qi, wrow);   // Ws, Wq, Wk, Wvo
    {
      float4 b4 = *reinterpret_cast<const float4*>(bs + colb);
#pragma unroll
      for (int nt = 0; nt < 3; nt++) {
        statpk[nt][0] = f2bf2(fmaxf(acc[0][nt][0] + b4.x, 0.f), fmaxf(acc[0][nt][1] + b4.y, 0.f));
        statpk[nt][1] = f2bf2(fmaxf(acc[0][nt][2] + b4.z, 0.f), fmaxf(acc[0][nt][3] + b4.w, 0.f));
      }
    }
    store_proj(&qbuf[0][0], acc[1], *reinterpret_cast<const float4*>(bq + colb), m0, colb);
    store_proj(&kbuf[0][0], acc[2], *reinterpret_cast<const float4*>(bk + colb), m0, colb);
    store_proj(&vbuf[0][0], acc[3], *reinterpret_cast<const float4*>(bvo + colb), m0, colb);
  }
  __syncthreads();

  for (int l = 0; l < NLAYERS; l++) {
    // ---- scores + 2-way softmax, 384 threads (one per (g,h,i,j)) ----
    if (tid < GB * NHEADS * SG * 2) {
      int js = tid & 1;
      int rest = tid >> 1;
      int i = rest % 3;
      int m = rest / 3;          // 0..63
      int h = m & 3, g = m >> 2;
      int j = (i == 0) ? (js ? 2 : 1) : (i == 1) ? (js ? 2 : 0) : (js ? 1 : 0);
      const uint4* qp = reinterpret_cast<const uint4*>(&qbuf[g * 3 + i][h * HD]);
      const uint4* kp = reinterpret_cast<const uint4*>(&kbuf[g * 3 + j][h * HD]);
      float s = 0.f;
#pragma unroll
      for (int c = 0; c < 4; c++) {
        uint4 qu = qp[c], ku = kp[c];
        u32 qs[4] = {qu.x, qu.y, qu.z, qu.w};
        u32 ks[4] = {ku.x, ku.y, ku.z, ku.w};
#pragma unroll
        for (int e = 0; e < 4; e++)
          s += bf2f_lo(qs[e]) * bf2f_lo(ks[e]) + bf2f_hi(qs[e]) * bf2f_hi(ks[e]);
      }
      s *= 0.17677669529663687f;   // 1/sqrt(32)
      float so = __shfl_xor(s, 1); // partner (other j); pairs are wave-aligned
      float mx = fmaxf(s, so);
      float e = __expf(s - mx), eo = __expf(so - mx);
      scratch[((g * NHEADS + h) * SG + i) * 2 + js] = e / (e + eo);
    }
    __syncthreads();

    // ---- combine: xdyn += beta*(P·V' + bo); V' is already O-projected.
    //      Also refresh xbf mirror for the next layer (xbf has no readers now).
    {
      float4 bo4 = *reinterpret_cast<const float4*>(bo + l * H + colb);
      const float betal = beta[l];
      const int h = colb >> 5;
#pragma unroll
      for (int nt = 0; nt < 3; nt++) {
        int r = nt * 16 + m0;
        int g = r / 3, i = r - g * 3;
        int j0 = (i == 0) ? 1 : 0;
        int j1 = (i == 2) ? 1 : 2;
        int ai = ((g * NHEADS + h) * SG + i) * 2;
        float a0 = scratch[ai + 0], a1 = scratch[ai + 1];
        uint2 v0 = *reinterpret_cast<const uint2*>(&vbuf[g * 3 + j0][colb]);
        uint2 v1 = *reinterpret_cast<const uint2*>(&vbuf[g * 3 + j1][colb]);
        xdyn[nt][0] += betal * (a0 * bf2f_lo(v0.x) + a1 * bf2f_lo(v1.x) + bo4.x);
        xdyn[nt][1] += betal * (a0 * bf2f_hi(v0.x) + a1 * bf2f_hi(v1.x) + bo4.y);
        xdyn[nt][2] += betal * (a0 * bf2f_lo(v0.y) + a1 * bf2f_lo(v1.y) + bo4.z);
        xdyn[nt][3] += betal * (a0 * bf2f_hi(v0.y) + a1 * bf2f_hi(v1.y) + bo4.w);
        if (l + 1 < NLAYERS) {
          uint2 pp;
          pp.x = f2bf2(xdyn[nt][0], xdyn[nt][1]);
          pp.y = f2bf2(xdyn[nt][2], xdyn[nt][3]);
          *reinterpret_cast<uint2*>(&xbf[r][colb]) = pp;
        }
      }
    }
    __syncthreads();   // fences: scratch/vbuf reads done, xbf writes visible

    if (l + 1 < NLAYERS) {
      // ---- Q/K/V' of layer l+1: ONE 3-stream pass, store-now.
      //      qbuf/kbuf last read in scores (2 barriers ago); vbuf in combine
      //      (1 barrier ago) -> all stores safe immediately.
      floatx4 acc[3][3];
      multi_proj<3>(&xbf[0][0], wt + (size_t)(1 + 3 * (l + 1)) * H * H, acc, m0, qi, wrow);
      store_proj(&qbuf[0][0], acc[0], *reinterpret_cast<const float4*>(bq + (l + 1) * H + colb), m0, colb);
      store_proj(&kbuf[0][0], acc[1], *reinterpret_cast<const float4*>(bk + (l + 1) * H + colb), m0, colb);
      store_proj(&vbuf[0][0], acc[2], *reinterpret_cast<const float4*>(bvo + (l + 1) * H + colb), m0, colb);
      __syncthreads();
    }
  }

  // ---- readout: gene score = sum_c (dyn-stat)^2 * Wp[c]; group mean ----
  float4 wp4 = *reinterpret_cast<const float4*>(Wp + colb);
  float rsum[3];
#pragma unroll
  for (int nt = 0; nt < 3; nt++) {
    float d0 = xdyn[nt][0] - bf2f_lo(statpk[nt][0]);
    float d1 = xdyn[nt][1] - bf2f_hi(statpk[nt][0]);
    float d2 = xdyn[nt][2] - bf2f_lo(statpk[nt][1]);
    float d3 = xdyn[nt][3] - bf2f_hi(statpk[nt][1]);
    rsum[nt] = d0 * d0 * wp4.x + d1 * d1 * wp4.y + d2 * d2 * wp4.z + d3 * d3 * wp4.w;
  }
  // reduce over qi (lane bits 4,5): each row's 16 cols within this wave
#pragma unroll
  for (int nt = 0; nt < 3; nt++) {
    rsum[nt] += __shfl_xor(rsum[nt], 16, 64);
    rsum[nt] += __shfl_xor(rsum[nt], 32, 64);
  }
  // scratch re-used as rowsc[MR][8]; last read (combine l=1) fenced by the
  // post-combine barrier
  if (qi == 0) {
#pragma unroll
    for (int nt = 0; nt < 3; nt++)
      scratch[(nt * 16 + m0) * 8 + wave] = rsum[nt];
  }
  __syncthreads();
  if (tid < GB) {
    float s = 0.f;
#pragma unroll
    for (int i = 0; i < SG; i++) {
      int row = tid * 3 + i;
#pragma unroll
      for (int w = 0; w < 8; w++) s += scratch[row * 8 + w];
    }
    out[blockIdx.x * GB + tid] = s * (1.f / 3.f) + bp[0];
  }
}

extern "C" void kernel_launch(void* const* d_in, const int* in_sizes, int n_in,
                              void* d_out, int out_size, void* d_ws, size_t ws_size,
                              hipStream_t stream) {
  const float* x    = (const float*)d_in[0];
  // d_in[1] = batch ids: deterministic repeat(arange(G),3) -> not needed
  const float* Ws   = (const float*)d_in[2];
  const float* bs   = (const float*)d_in[3];
  const float* Wq   = (const float*)d_in[4];
  const float* bq   = (const float*)d_in[5];
  const float* Wk   = (const float*)d_in[6];
  const float* bk   = (const float*)d_in[7];
  const float* Wv   = (const float*)d_in[8];
  const float* bv   = (const float*)d_in[9];
  const float* Wo   = (const float*)d_in[10];
  const float* bo   = (const float*)d_in[11];
  const float* beta = (const float*)d_in[12];
  const float* Wp   = (const float*)d_in[13];
  const float* bp   = (const float*)d_in[14];
  float* out = (float*)d_out;
  u16* wt = (u16*)d_ws;   // 7*16384 bf16 + 2*128 f32 = 230,400 B (ws >= 294,912)

  // ws is re-poisoned before every launch -> convert every call
  wconv_t<<<320, 256, 0, stream>>>(Ws, Wq, Wk, wt);
  wvo_kernel<<<129, 256, 0, stream>>>(Wv, Wo, bv, wt);
  dango_kernel<<<NGROUPS / GB, NT, 0, stream>>>(x, wt, bs, bq, bk, bo, beta, Wp, bp, out);
}